// Round 6
// baseline (675.660 us; speedup 1.0000x reference)
//
#include <hip/hip_runtime.h>
#include <hip/hip_bf16.h>

// Problem dims (fixed)
#define N_LIG   10000
#define N_PROT  40000
#define NN      50000     // total nodes
#define EDGES   400000
#define BATCH   512
#define F_LIG   74
#define F_PROT  1280
#define HD      256       // H*D
#define HEADS   4
#define DIM     64

typedef __bf16 bf16x8 __attribute__((ext_vector_type(8)));
typedef __bf16 bf16x4 __attribute__((ext_vector_type(4)));
typedef float  f32x4  __attribute__((ext_vector_type(4)));

// ---------------- CSR build ----------------

__global__ void k_hist(const int* __restrict__ dst, int* __restrict__ counts, int E) {
    int e = blockIdx.x * blockDim.x + threadIdx.x;
    if (e < E) atomicAdd(&counts[dst[e]], 1);
}

__global__ __launch_bounds__(1024) void k_scan1(const int* __restrict__ counts,
                                                int* __restrict__ incl,
                                                int* __restrict__ bsum, int N) {
    __shared__ int tmp[1024];
    int i = blockIdx.x * 1024 + threadIdx.x;
    int v = (i < N) ? counts[i] : 0;
    tmp[threadIdx.x] = v;
    __syncthreads();
    for (int off = 1; off < 1024; off <<= 1) {
        int add = (threadIdx.x >= (unsigned)off) ? tmp[threadIdx.x - off] : 0;
        __syncthreads();
        tmp[threadIdx.x] += add;
        __syncthreads();
    }
    if (i < N) incl[i] = tmp[threadIdx.x];
    if (threadIdx.x == 1023) bsum[blockIdx.x] = tmp[1023];
}

__global__ void k_scan2(int* __restrict__ bsum, int nb, int* __restrict__ row_ptr, int N, int E) {
    if (threadIdx.x == 0 && blockIdx.x == 0) {
        int run = 0;
        for (int i = 0; i < nb; ++i) { int v = bsum[i]; bsum[i] = run; run += v; }
        row_ptr[N] = E;
    }
}

__global__ __launch_bounds__(1024) void k_scan3(const int* __restrict__ incl,
                                                const int* __restrict__ counts,
                                                const int* __restrict__ bsum,
                                                int* __restrict__ row_ptr, int N) {
    int i = blockIdx.x * 1024 + threadIdx.x;
    if (i < N) row_ptr[i] = bsum[blockIdx.x] + incl[i] - counts[i];  // exclusive
}

__global__ void k_scatter(const int* __restrict__ src, const int* __restrict__ dst,
                          const int* __restrict__ row_ptr, int* __restrict__ cursor,
                          int* __restrict__ csr_src, int E) {
    int e = blockIdx.x * blockDim.x + threadIdx.x;
    if (e < E) {
        int d = dst[e];
        int pos = row_ptr[d] + atomicAdd(&cursor[d], 1);
        csr_src[pos] = src[e];
    }
}

// ---------------- weight transpose+convert: W f32 [K,256] -> Bt bf16 [256][Kp] ----------------
__global__ __launch_bounds__(256) void k_wcvt(const float* __restrict__ W,
                                              __bf16* __restrict__ Bt, int K, int Kp) {
    int n = blockIdx.x;   // 0..255
    for (int k = threadIdx.x; k < Kp; k += blockDim.x)
        Bt[(size_t)n * Kp + k] = (k < K) ? (__bf16)W[(size_t)k * HD + n] : (__bf16)0.f;
}

// ---------------- ligand A pad: [N_LIG,74] f32 -> [N_LIG,96] f32 (zero tail) ----------------
__global__ __launch_bounds__(128) void k_apad(const float* __restrict__ A, float* __restrict__ Ap) {
    int row = blockIdx.x, t = threadIdx.x;
    if (t < 96) Ap[(size_t)row * 96 + t] = (t < F_LIG) ? A[(size_t)row * F_LIG + t] : 0.f;
}

// ---------------- async global->LDS helper (width 16) ----------------
__device__ __forceinline__ void gload16(const void* g, void* l) {
    __builtin_amdgcn_global_load_lds(
        (const __attribute__((address_space(1))) void*)g,
        (__attribute__((address_space(3))) void*)l, 16, 0, 0);
}

// m204 bijective XCD swizzle
__device__ __forceinline__ int xcd_swz(int orig, int nwg) {
    int q = nwg >> 3, r = nwg & 7;
    int xcd = orig & 7, idx = orig >> 3;
    return (xcd < r ? xcd * (q + 1) : r * (q + 1) + (xcd - r) * q) + idx;
}

// ---------------- MFMA GEMM: 4-deep gload_lds pipeline, counted vmcnt ----------------
// R5 post-mortem: depth-3 gives stage(s+1) only ~1 step-time of slack before its wait
// -> partially exposed HBM latency (~900cyc vs ~650cyc step) on the half of A that
// misses L3 (FETCH 106/205MB). Depth-4 + vmcnt(8): stage(s+1) issued at step s-2,
// waited at end of s -> 2 step-times of slack > HBM latency. LDS 64KB -> 2 blocks/CU
// (measured residency at depth-3 was already 2.15, so ~free).
// Swizzled LDS (rule 21, both-sides): A-row r slot d holds kchunk d^(r&7); B: d^(r&3).
// K%32==0 (ligand pre-padded to 96); M-tail rows clamp SOURCE addr to M-1.
// MODE=0 (proj): A->bf16 hi only -> C f32.  MODE=1 (layer): hi/lo split, Hbf + fused att.
template <int MODE>
__global__ __launch_bounds__(256, 2)
void mfma_gemm(const float* __restrict__ A, const __bf16* __restrict__ Bt,
               float* __restrict__ C,
               __bf16* __restrict__ Hbf, float* __restrict__ atts, float* __restrict__ attd,
               const float* __restrict__ a_src, const float* __restrict__ a_dst,
               int M, int K, int Kp, int nwg) {
    __shared__ __align__(16) unsigned char smem[65536];
    float*  sA = (float*)smem;             // 4 x 2048 f32  = 32KB
    __bf16* sB = (__bf16*)(smem + 32768);  // 4 x 4096 bf16 = 32KB

    int wg   = xcd_swz(blockIdx.x, nwg);
    int tid  = threadIdx.x;
    int bm   = (wg >> 1) * 64;
    int bn   = (wg & 1) * 128;
    int lane = tid & 63, wave = tid >> 6;
    int wr   = wave >> 1, wc = wave & 1;
    int l15  = lane & 15, quad = lane >> 4;

    f32x4 acc[2][4];
    #pragma unroll
    for (int i = 0; i < 2; ++i)
        #pragma unroll
        for (int j = 0; j < 4; ++j)
            acc[i][j] = (f32x4){0.f, 0.f, 0.f, 0.f};

    // staging geometry: 4 waves x 2 chunks of 1KB for A and for B (4 gload16/thread/stage)
    int caA = wave * 2;
    int rlA = lane >> 3, csA = (lane & 7) ^ rlA;
    int rlB = lane >> 2, csB = (lane & 3) ^ (rlB & 3);

    int gmA[2];
    const __bf16* gB[2];
    #pragma unroll
    for (int it = 0; it < 2; ++it) {
        int gm = bm + (caA + it) * 8 + rlA;
        gmA[it] = (gm < M) ? gm : (M - 1);
        gB[it] = Bt + (size_t)(bn + (caA + it) * 16 + rlB) * Kp + csB * 8;
    }

    auto stage = [&](int buf, int k0) {
        #pragma unroll
        for (int it = 0; it < 2; ++it)
            gload16(A + (size_t)gmA[it] * K + k0 + csA * 4,
                    sA + buf * 2048 + (caA + it) * 256);
        #pragma unroll
        for (int it = 0; it < 2; ++it)
            gload16(gB[it] + k0,
                    sB + buf * 4096 + (caA + it) * 512);
    };

    int nsteps = K >> 5;

    // ---- prologue: fill pipeline up to 3 deep ----
    stage(0, 0);
    if (nsteps > 1) stage(1, 32);
    if (nsteps > 2) stage(2, 64);
    if (nsteps > 2)      { asm volatile("s_waitcnt vmcnt(8)" ::: "memory"); }
    else if (nsteps > 1) { asm volatile("s_waitcnt vmcnt(4)" ::: "memory"); }
    else                 { asm volatile("s_waitcnt vmcnt(0)" ::: "memory"); }
    __builtin_amdgcn_s_barrier();
    __builtin_amdgcn_sched_barrier(0);

    int cur = 0, stg = 3;   // cur = s%4 ; stg = (s+3)%4
    for (int s = 0; s < nsteps; ++s) {
        if (s + 3 < nsteps) stage(stg, (s + 3) * 32);   // overwrites buf read at step s-1

        // ---- fragment loads (swizzled, bank-uniform) ----
        bf16x8 bfr[4];
        #pragma unroll
        for (int j = 0; j < 4; ++j) {
            int rowb = wc * 64 + j * 16 + l15;
            int ch = quad ^ (l15 & 3);
            bfr[j] = *(const bf16x8*)&sB[cur * 4096 + rowb * 32 + ch * 8];
        }
        bf16x8 af[2], al[2];
        #pragma unroll
        for (int i = 0; i < 2; ++i) {
            int rowa = wr * 32 + i * 16 + l15;
            int ch0 = (quad * 2)     ^ (l15 & 7);
            int ch1 = (quad * 2 + 1) ^ (l15 & 7);
            f32x4 p0 = *(const f32x4*)&sA[cur * 2048 + rowa * 32 + ch0 * 4];
            f32x4 p1 = *(const f32x4*)&sA[cur * 2048 + rowa * 32 + ch1 * 4];
            #pragma unroll
            for (int c = 0; c < 8; ++c) {
                float x = (c < 4) ? p0[c] : p1[c - 4];
                __bf16 h = (__bf16)x;
                af[i][c] = h;
                if (MODE) al[i][c] = (__bf16)(x - (float)h);
            }
        }

        #pragma unroll
        for (int i = 0; i < 2; ++i)
            #pragma unroll
            for (int j = 0; j < 4; ++j) {
                acc[i][j] = __builtin_amdgcn_mfma_f32_16x16x32_bf16(af[i], bfr[j], acc[i][j], 0, 0, 0);
                if (MODE)
                    acc[i][j] = __builtin_amdgcn_mfma_f32_16x16x32_bf16(al[i], bfr[j], acc[i][j], 0, 0, 0);
            }

        // ---- step edge: drain this step's ds_reads; counted-wait for next buf ----
        asm volatile("s_waitcnt lgkmcnt(0)" ::: "memory");
        __builtin_amdgcn_sched_barrier(0);
        if (s + 3 < nsteps)      { asm volatile("s_waitcnt vmcnt(8)" ::: "memory"); }
        else if (s + 2 < nsteps) { asm volatile("s_waitcnt vmcnt(4)" ::: "memory"); }
        else if (s + 1 < nsteps) { asm volatile("s_waitcnt vmcnt(0)" ::: "memory"); }
        __builtin_amdgcn_s_barrier();
        __builtin_amdgcn_sched_barrier(0);

        cur = (cur + 1) & 3;
        stg = (stg + 1) & 3;
    }

    // ---- epilogue: C/D layout col=lane&15, row=quad*4+reg ----
    if (MODE == 0) {
        #pragma unroll
        for (int i = 0; i < 2; ++i)
            #pragma unroll
            for (int r = 0; r < 4; ++r) {
                int m = bm + wr * 32 + i * 16 + quad * 4 + r;
                if (m < M) {
                    #pragma unroll
                    for (int j = 0; j < 4; ++j)
                        C[(size_t)m * HD + bn + wc * 64 + j * 16 + l15] = acc[i][j][r];
                }
            }
    } else {
        int head = (bn >> 6) + wc;
        float as[4], ad2[4];
        #pragma unroll
        for (int j = 0; j < 4; ++j) {
            as[j]  = a_src[head * DIM + j * 16 + l15];
            ad2[j] = a_dst[head * DIM + j * 16 + l15];
        }
        #pragma unroll
        for (int i = 0; i < 2; ++i)
            #pragma unroll
            for (int r = 0; r < 4; ++r) {
                int m = bm + wr * 32 + i * 16 + quad * 4 + r;
                bool ok = m < M;
                float s = 0.f, t = 0.f;
                #pragma unroll
                for (int j = 0; j < 4; ++j) {
                    float v = acc[i][j][r];
                    if (ok) Hbf[(size_t)m * HD + head * DIM + j * 16 + l15] = (__bf16)v;
                    s += v * as[j];
                    t += v * ad2[j];
                }
                #pragma unroll
                for (int mask = 1; mask <= 8; mask <<= 1) {
                    s += __shfl_xor(s, mask, 64);
                    t += __shfl_xor(t, mask, 64);
                }
                if (ok && l15 == 0) {
                    atts[m * HEADS + head] = s;
                    attd[m * HEADS + head] = t;
                }
            }
    }
}

// ---------------- GAT edge-softmax + aggregation: wave-per-node, 4 heads fused ----------------
__global__ __launch_bounds__(256) void gat_agg(const __bf16* __restrict__ hW,
                                               const float* __restrict__ att_s,
                                               const float* __restrict__ att_d,
                                               const int* __restrict__ row_ptr,
                                               const int* __restrict__ csr_src,
                                               float* __restrict__ out, int N) {
    int n = blockIdx.x * 4 + (threadIdx.x >> 6);
    if (n >= N) return;
    int lane = threadIdx.x & 63;
    int sub  = lane >> 4;     // edge slot within 4-edge group
    int dq   = lane & 15;     // dim quarter within a head
    int r0 = row_ptr[n], deg = row_ptr[n + 1] - r0;
    f32x4 ad4 = *(const f32x4*)&att_d[n * HEADS];

    f32x4 acc[4];             // [head][4 dims]
    #pragma unroll
    for (int h = 0; h < HEADS; ++h) acc[h] = (f32x4){0.f, 0.f, 0.f, 0.f};
    f32x4 wsum4 = (f32x4){0.f, 0.f, 0.f, 0.f};

    if (deg <= 64) {
        bool act = lane < deg;
        int sj = act ? csr_src[r0 + lane] : 0;
        f32x4 a4 = act ? *(const f32x4*)&att_s[sj * HEADS] : (f32x4){0.f, 0.f, 0.f, 0.f};
        f32x4 x4;
        #pragma unroll
        for (int h = 0; h < HEADS; ++h) {
            float v = a4[h] + ad4[h];
            v = (v >= 0.f) ? v : 0.2f * v;
            x4[h] = act ? v : -INFINITY;
        }
        f32x4 m4 = x4;
        for (int off = 32; off > 0; off >>= 1)
            #pragma unroll
            for (int h = 0; h < HEADS; ++h)
                m4[h] = fmaxf(m4[h], __shfl_xor(m4[h], off, 64));
        f32x4 w4;
        #pragma unroll
        for (int h = 0; h < HEADS; ++h)
            w4[h] = act ? expf(x4[h] - m4[h]) : 0.f;
        wsum4 = w4;

        for (int g0 = 0; g0 < deg; g0 += 4) {
            int e  = g0 + sub;
            int ec = min(e, deg - 1);
            int se = __shfl(sj, ec, 64);
            bool eact = e < deg;
            #pragma unroll
            for (int h = 0; h < HEADS; ++h) {
                float wh = __shfl(w4[h], ec, 64);
                if (!eact) wh = 0.f;
                bf16x4 v = *(const bf16x4*)&hW[(size_t)se * HD + h * DIM + dq * 4];
                #pragma unroll
                for (int c = 0; c < 4; ++c) acc[h][c] += wh * (float)v[c];
            }
        }
    } else {
        f32x4 m4 = (f32x4){-INFINITY, -INFINITY, -INFINITY, -INFINITY};
        for (int base = 0; base < deg; base += 64) {
            int i = base + lane;
            bool act = i < deg;
            int sj = act ? csr_src[r0 + i] : 0;
            f32x4 a4 = act ? *(const f32x4*)&att_s[sj * HEADS] : (f32x4){0.f, 0.f, 0.f, 0.f};
            #pragma unroll
            for (int h = 0; h < HEADS; ++h) {
                float v = a4[h] + ad4[h];
                v = (v >= 0.f) ? v : 0.2f * v;
                m4[h] = fmaxf(m4[h], act ? v : -INFINITY);
            }
        }
        for (int off = 32; off > 0; off >>= 1)
            #pragma unroll
            for (int h = 0; h < HEADS; ++h)
                m4[h] = fmaxf(m4[h], __shfl_xor(m4[h], off, 64));

        for (int base = 0; base < deg; base += 64) {
            int i = base + lane;
            bool act = i < deg;
            int sj = act ? csr_src[r0 + i] : 0;
            f32x4 a4 = act ? *(const f32x4*)&att_s[sj * HEADS] : (f32x4){0.f, 0.f, 0.f, 0.f};
            f32x4 w4;
            #pragma unroll
            for (int h = 0; h < HEADS; ++h) {
                float v = a4[h] + ad4[h];
                v = (v >= 0.f) ? v : 0.2f * v;
                w4[h] = act ? expf(v - m4[h]) : 0.f;
            }
            #pragma unroll
            for (int h = 0; h < HEADS; ++h) wsum4[h] += w4[h];
            int cnt = min(64, deg - base);
            for (int g0 = 0; g0 < cnt; g0 += 4) {
                int e  = g0 + sub;
                int ec = min(e, cnt - 1);
                int se = __shfl(sj, ec, 64);
                bool eact = e < cnt;
                #pragma unroll
                for (int h = 0; h < HEADS; ++h) {
                    float wh = __shfl(w4[h], ec, 64);
                    if (!eact) wh = 0.f;
                    bf16x4 v = *(const bf16x4*)&hW[(size_t)se * HD + h * DIM + dq * 4];
                    #pragma unroll
                    for (int c = 0; c < 4; ++c) acc[h][c] += wh * (float)v[c];
                }
            }
        }
    }

    #pragma unroll
    for (int h = 0; h < HEADS; ++h)
        #pragma unroll
        for (int c = 0; c < 4; ++c) {
            acc[h][c] += __shfl_xor(acc[h][c], 16, 64);
            acc[h][c] += __shfl_xor(acc[h][c], 32, 64);
        }
    for (int off = 32; off > 0; off >>= 1)
        #pragma unroll
        for (int h = 0; h < HEADS; ++h)
            wsum4[h] += __shfl_xor(wsum4[h], off, 64);

    if (sub == 0) {
        #pragma unroll
        for (int h = 0; h < HEADS; ++h) {
            float inv = 1.f / (wsum4[h] + 1e-9f);
            f32x4 o;
            #pragma unroll
            for (int c = 0; c < 4; ++c) {
                float v = acc[h][c] * inv;
                o[c] = (v > 0.f) ? v : expm1f(v);  // ELU
            }
            *(f32x4*)&out[(size_t)n * HD + h * DIM + dq * 4] = o;
        }
    }
}

// ---------------- mean pool per graph + final linear (f32 output) ----------------
__global__ __launch_bounds__(256) void pool_out(const float* __restrict__ h,
                                                const int* __restrict__ gid,
                                                const float* __restrict__ W_out,
                                                const float* __restrict__ b_out,
                                                const float* __restrict__ scores,
                                                float* __restrict__ out, int N) {
    int b = blockIdx.x;
    int j = threadIdx.x;
    int l = 0, r = N;
    while (l < r) { int mid = (l + r) >> 1; if (gid[mid] < b) l = mid + 1; else r = mid; }
    int lo = l;
    r = N;
    while (l < r) { int mid = (l + r) >> 1; if (gid[mid] < b + 1) l = mid + 1; else r = mid; }
    int hi = l;

    float sum = 0.f;
    for (int n = lo; n < hi; ++n) sum += h[(size_t)n * HD + j];
    int cnt = hi - lo;
    float pooled = sum / fmaxf((float)cnt, 1.f);
    float val = pooled * W_out[j];

    __shared__ float red[256];
    red[j] = val;
    __syncthreads();
    for (int s = 128; s > 0; s >>= 1) {
        if (j < s) red[j] += red[j + s];
        __syncthreads();
    }
    if (j == 0) {
        out[b] = red[0] + scores[b] * W_out[HD] + b_out[0];
    }
}

// ---------------- host ----------------

static inline size_t al256(size_t x) { return (x + 255) & ~(size_t)255; }

#define KP_LIG  96
#define KP_PROT 1280
#define KP_HID  256

extern "C" void kernel_launch(void* const* d_in, const int* in_sizes, int n_in,
                              void* d_out, int out_size, void* d_ws, size_t ws_size,
                              hipStream_t stream) {
    const float* ligand_x  = (const float*)d_in[0];
    const float* protein_x = (const float*)d_in[1];
    const float* W_lig     = (const float*)d_in[2];
    const float* W_prot    = (const float*)d_in[3];
    const float* W1        = (const float*)d_in[4];
    const float* a1_src    = (const float*)d_in[5];
    const float* a1_dst    = (const float*)d_in[6];
    const float* W2        = (const float*)d_in[7];
    const float* a2_src    = (const float*)d_in[8];
    const float* a2_dst    = (const float*)d_in[9];
    const float* W_out     = (const float*)d_in[10];
    const float* b_out     = (const float*)d_in[11];
    const int*   edge_src  = (const int*)d_in[12];
    const int*   edge_dst  = (const int*)d_in[13];
    const int*   graph_ids = (const int*)d_in[14];
    const float* scores    = (const float*)d_in[15];
    float* out = (float*)d_out;

    // workspace layout
    char* w = (char*)d_ws;
    float*  xbuf = (float*)w;           w += al256((size_t)NN * HD * 4);
    __bf16* Hbf  = (__bf16*)w;          w += al256((size_t)NN * HD * 2);
    float* atts = (float*)w;            w += al256((size_t)NN * HEADS * 4);
    float* attd = (float*)w;            w += al256((size_t)NN * HEADS * 4);
    int* counts  = (int*)w;             w += al256((size_t)NN * 4);
    int* incl    = (int*)w;             w += al256((size_t)NN * 4);
    int* bsum    = (int*)w;             w += al256(64 * 4);
    int* row_ptr = (int*)w;             w += al256((size_t)(NN + 1) * 4);
    int* cursor  = (int*)w;             w += al256((size_t)NN * 4);
    int* csr_src = (int*)w;             w += al256((size_t)EDGES * 4);
    __bf16* Bt_lig  = (__bf16*)w;       w += al256((size_t)HD * KP_LIG * 2);
    __bf16* Bt_prot = (__bf16*)w;       w += al256((size_t)HD * KP_PROT * 2);
    __bf16* Bt_W1   = (__bf16*)w;       w += al256((size_t)HD * KP_HID * 2);
    __bf16* Bt_W2   = (__bf16*)w;       w += al256((size_t)HD * KP_HID * 2);
    float* Apad     = (float*)w;        w += al256((size_t)N_LIG * KP_LIG * 4);

    const int NB_SCAN = (NN + 1023) / 1024;  // 49

    hipMemsetAsync(counts, 0, (size_t)NN * 4, stream);
    hipMemsetAsync(cursor, 0, (size_t)NN * 4, stream);

    // --- weight convert/transpose to bf16; ligand A zero-pad to K=96 ---
    k_wcvt<<<HD, 256, 0, stream>>>(W_lig,  Bt_lig,  F_LIG,  KP_LIG);
    k_wcvt<<<HD, 256, 0, stream>>>(W_prot, Bt_prot, F_PROT, KP_PROT);
    k_wcvt<<<HD, 256, 0, stream>>>(W1,     Bt_W1,   HD,     KP_HID);
    k_wcvt<<<HD, 256, 0, stream>>>(W2,     Bt_W2,   HD,     KP_HID);
    k_apad<<<N_LIG, 128, 0, stream>>>(ligand_x, Apad);

    // --- CSR by destination ---
    k_hist<<<(EDGES + 255) / 256, 256, 0, stream>>>(edge_dst, counts, EDGES);
    k_scan1<<<NB_SCAN, 1024, 0, stream>>>(counts, incl, bsum, NN);
    k_scan2<<<1, 1, 0, stream>>>(bsum, NB_SCAN, row_ptr, NN, EDGES);
    k_scan3<<<NB_SCAN, 1024, 0, stream>>>(incl, counts, bsum, row_ptr, NN);
    k_scatter<<<(EDGES + 255) / 256, 256, 0, stream>>>(edge_src, edge_dst, row_ptr,
                                                       cursor, csr_src, EDGES);

    // --- input projections -> xbuf [NN,256] (4-deep counted GEMM) ---
    {
        int nwg = 2 * ((N_LIG + 63) / 64);
        mfma_gemm<0><<<nwg, 256, 0, stream>>>(
            Apad, Bt_lig, xbuf, nullptr, nullptr, nullptr, nullptr, nullptr,
            N_LIG, KP_LIG, KP_LIG, nwg);
    }
    {
        int nwg = 2 * ((N_PROT + 63) / 64);
        mfma_gemm<0><<<nwg, 256, 0, stream>>>(
            protein_x, Bt_prot, xbuf + (size_t)N_LIG * HD, nullptr, nullptr, nullptr,
            nullptr, nullptr, N_PROT, KP_PROT, KP_PROT, nwg);
    }

    // --- GAT layer 1: GEMM (+fused att, bf16 h) -> gather ---
    {
        int nwg = 2 * ((NN + 63) / 64);
        mfma_gemm<1><<<nwg, 256, 0, stream>>>(
            xbuf, Bt_W1, nullptr, Hbf, atts, attd, a1_src, a1_dst, NN, KP_HID, KP_HID, nwg);
    }
    gat_agg<<<(NN + 3) / 4, 256, 0, stream>>>(Hbf, atts, attd, row_ptr, csr_src, xbuf, NN);

    // --- GAT layer 2 ---
    {
        int nwg = 2 * ((NN + 63) / 64);
        mfma_gemm<1><<<nwg, 256, 0, stream>>>(
            xbuf, Bt_W2, nullptr, Hbf, atts, attd, a2_src, a2_dst, NN, KP_HID, KP_HID, nwg);
    }
    gat_agg<<<(NN + 3) / 4, 256, 0, stream>>>(Hbf, atts, attd, row_ptr, csr_src, xbuf, NN);

    // --- pool + final linear ---
    pool_out<<<BATCH, 256, 0, stream>>>(xbuf, graph_ids, W_out, b_out, scores, out, NN);
}

// Round 7
// 660.154 us; speedup vs baseline: 1.0235x; 1.0235x over previous
//
#include <hip/hip_runtime.h>
#include <hip/hip_bf16.h>

// Problem dims (fixed)
#define N_LIG   10000
#define N_PROT  40000
#define NN      50000     // total nodes
#define EDGES   400000
#define BATCH   512
#define F_LIG   74
#define F_PROT  1280
#define HD      256       // H*D
#define HEADS   4
#define DIM     64

typedef __bf16 bf16x8 __attribute__((ext_vector_type(8)));
typedef __bf16 bf16x4 __attribute__((ext_vector_type(4)));
typedef float  f32x4  __attribute__((ext_vector_type(4)));

// ---------------- CSR build ----------------

__global__ void k_hist(const int* __restrict__ dst, int* __restrict__ counts, int E) {
    int e = blockIdx.x * blockDim.x + threadIdx.x;
    if (e < E) atomicAdd(&counts[dst[e]], 1);
}

__global__ __launch_bounds__(1024) void k_scan1(const int* __restrict__ counts,
                                                int* __restrict__ incl,
                                                int* __restrict__ bsum, int N) {
    __shared__ int tmp[1024];
    int i = blockIdx.x * 1024 + threadIdx.x;
    int v = (i < N) ? counts[i] : 0;
    tmp[threadIdx.x] = v;
    __syncthreads();
    for (int off = 1; off < 1024; off <<= 1) {
        int add = (threadIdx.x >= (unsigned)off) ? tmp[threadIdx.x - off] : 0;
        __syncthreads();
        tmp[threadIdx.x] += add;
        __syncthreads();
    }
    if (i < N) incl[i] = tmp[threadIdx.x];
    if (threadIdx.x == 1023) bsum[blockIdx.x] = tmp[1023];
}

__global__ void k_scan2(int* __restrict__ bsum, int nb, int* __restrict__ row_ptr, int N, int E) {
    if (threadIdx.x == 0 && blockIdx.x == 0) {
        int run = 0;
        for (int i = 0; i < nb; ++i) { int v = bsum[i]; bsum[i] = run; run += v; }
        row_ptr[N] = E;
    }
}

__global__ __launch_bounds__(1024) void k_scan3(const int* __restrict__ incl,
                                                const int* __restrict__ counts,
                                                const int* __restrict__ bsum,
                                                int* __restrict__ row_ptr, int N) {
    int i = blockIdx.x * 1024 + threadIdx.x;
    if (i < N) row_ptr[i] = bsum[blockIdx.x] + incl[i] - counts[i];  // exclusive
}

__global__ void k_scatter(const int* __restrict__ src, const int* __restrict__ dst,
                          const int* __restrict__ row_ptr, int* __restrict__ cursor,
                          int* __restrict__ csr_src, int E) {
    int e = blockIdx.x * blockDim.x + threadIdx.x;
    if (e < E) {
        int d = dst[e];
        int pos = row_ptr[d] + atomicAdd(&cursor[d], 1);
        csr_src[pos] = src[e];
    }
}

// ---------------- weight transpose+convert: W f32 [K,256] -> Bt bf16 [256][Kp] ----------------
__global__ __launch_bounds__(256) void k_wcvt(const float* __restrict__ W,
                                              __bf16* __restrict__ Bt, int K, int Kp) {
    int n = blockIdx.x;   // 0..255
    for (int k = threadIdx.x; k < Kp; k += blockDim.x)
        Bt[(size_t)n * Kp + k] = (k < K) ? (__bf16)W[(size_t)k * HD + n] : (__bf16)0.f;
}

// ---------------- ligand A pad: [N_LIG,74] f32 -> [N_LIG,96] f32 (zero tail) ----------------
__global__ __launch_bounds__(128) void k_apad(const float* __restrict__ A, float* __restrict__ Ap) {
    int row = blockIdx.x, t = threadIdx.x;
    if (t < 96) Ap[(size_t)row * 96 + t] = (t < F_LIG) ? A[(size_t)row * F_LIG + t] : 0.f;
}

// ---------------- async global->LDS helper (width 16) ----------------
__device__ __forceinline__ void gload16(const void* g, void* l) {
    __builtin_amdgcn_global_load_lds(
        (const __attribute__((address_space(1))) void*)g,
        (__attribute__((address_space(3))) void*)l, 16, 0, 0);
}

// m204 bijective XCD swizzle
__device__ __forceinline__ int xcd_swz(int orig, int nwg) {
    int q = nwg >> 3, r = nwg & 7;
    int xcd = orig & 7, idx = orig >> 3;
    return (xcd < r ? xcd * (q + 1) : r * (q + 1) + (xcd - r) * q) + idx;
}

// ---------------- MFMA GEMM: 64x256 tile, 3-deep gload_lds pipeline, counted vmcnt ----------
// R6 post-mortem: depth-4 == depth-3 (131 vs 129.6us) -> exposed-latency theory dead.
// Per-step accounting: ~800cyc pipe work + ~800cyc FIXED orchestration (2 barriers,
// lgkm drain, waitcnt). Lever = amortization: 2x work per step at constant overhead.
// Tile 64x256 (one col-block per row-block): 4 waves, wave = 64 rows x 64 cols
// (= one head in MODE1), 4x4 frags, 16 MFMA/wave/step (MODE0).
// Depth-3 (measured best), 6 gload16/thread/stage -> steady-state vmcnt(6).
// Swizzled LDS (rule 21, both-sides): A-row r slot d holds kchunk d^(r&7); B: d^(r&3).
// K%32==0 (ligand pre-padded to 96); M-tail rows clamp SOURCE addr to M-1.
// MODE=0 (proj): A->bf16 hi only -> C f32.  MODE=1 (layer): hi/lo split, Hbf + fused att.
template <int MODE>
__global__ __launch_bounds__(256, 2)
void mfma_gemm(const float* __restrict__ A, const __bf16* __restrict__ Bt,
               float* __restrict__ C,
               __bf16* __restrict__ Hbf, float* __restrict__ atts, float* __restrict__ attd,
               const float* __restrict__ a_src, const float* __restrict__ a_dst,
               int M, int K, int Kp, int nwg) {
    __shared__ __align__(16) unsigned char smem[73728];
    float*  sA = (float*)smem;             // 3 x 2048 f32  = 24KB  (64 rows x 32 k)
    __bf16* sB = (__bf16*)(smem + 24576);  // 3 x 8192 bf16 = 48KB  (256 rows x 32 k)

    int wg   = xcd_swz(blockIdx.x, nwg);
    int tid  = threadIdx.x;
    int bm   = wg * 64;
    int lane = tid & 63, wave = tid >> 6;
    int l15  = lane & 15, quad = lane >> 4;

    f32x4 acc[4][4];
    #pragma unroll
    for (int i = 0; i < 4; ++i)
        #pragma unroll
        for (int j = 0; j < 4; ++j)
            acc[i][j] = (f32x4){0.f, 0.f, 0.f, 0.f};

    // staging geometry:
    // A chunk ca = wave*2+it (0..7): rows ca*8+(lane>>3), dest slot lane&7,
    //   src kchunk (lane&7)^(lane>>3)           -> 2 gload16/thread
    // B chunk cb = wave*4+it (0..15): rows cb*16+(lane>>2), dest slot lane&3,
    //   src kchunk (lane&3)^((lane>>2)&3)       -> 4 gload16/thread
    int rlA = lane >> 3, csA = (lane & 7) ^ rlA;
    int rlB = lane >> 2, csB = (lane & 3) ^ (rlB & 3);

    int gmA[2];
    const __bf16* gB[4];
    #pragma unroll
    for (int it = 0; it < 2; ++it) {
        int gm = bm + (wave * 2 + it) * 8 + rlA;
        gmA[it] = (gm < M) ? gm : (M - 1);
    }
    #pragma unroll
    for (int it = 0; it < 4; ++it)
        gB[it] = Bt + (size_t)((wave * 4 + it) * 16 + rlB) * Kp + csB * 8;

    auto stage = [&](int buf, int k0) {
        #pragma unroll
        for (int it = 0; it < 2; ++it)
            gload16(A + (size_t)gmA[it] * K + k0 + csA * 4,
                    sA + buf * 2048 + (wave * 2 + it) * 256);
        #pragma unroll
        for (int it = 0; it < 4; ++it)
            gload16(gB[it] + k0,
                    sB + buf * 8192 + (wave * 4 + it) * 512);
    };

    int nsteps = K >> 5;   // >= 3 for all call sites

    // ---- prologue: fill 2 deep ----
    stage(0, 0);
    if (nsteps > 1) {
        stage(1, 32);
        asm volatile("s_waitcnt vmcnt(6)" ::: "memory");   // buf0 complete
    } else {
        asm volatile("s_waitcnt vmcnt(0)" ::: "memory");
    }
    __builtin_amdgcn_s_barrier();
    __builtin_amdgcn_sched_barrier(0);

    int cur = 0, stg = 2;   // cur = s%3 ; stg = (s+2)%3
    for (int s = 0; s < nsteps; ++s) {
        if (s + 2 < nsteps) stage(stg, (s + 2) * 32);

        // ---- fragment loads (swizzled, bank-aligned) ----
        bf16x8 bfr[4];
        #pragma unroll
        for (int j = 0; j < 4; ++j) {
            int rowb = wave * 64 + j * 16 + l15;
            int ch = quad ^ (l15 & 3);
            bfr[j] = *(const bf16x8*)&sB[cur * 8192 + rowb * 32 + ch * 8];
        }
        bf16x8 af[4], al[4];
        #pragma unroll
        for (int i = 0; i < 4; ++i) {
            int rowa = i * 16 + l15;
            int ch0 = (quad * 2)     ^ (l15 & 7);
            int ch1 = (quad * 2 + 1) ^ (l15 & 7);
            f32x4 p0 = *(const f32x4*)&sA[cur * 2048 + rowa * 32 + ch0 * 4];
            f32x4 p1 = *(const f32x4*)&sA[cur * 2048 + rowa * 32 + ch1 * 4];
            #pragma unroll
            for (int c = 0; c < 8; ++c) {
                float x = (c < 4) ? p0[c] : p1[c - 4];
                __bf16 h = (__bf16)x;
                af[i][c] = h;
                if (MODE) al[i][c] = (__bf16)(x - (float)h);
            }
        }

        #pragma unroll
        for (int i = 0; i < 4; ++i)
            #pragma unroll
            for (int j = 0; j < 4; ++j) {
                acc[i][j] = __builtin_amdgcn_mfma_f32_16x16x32_bf16(af[i], bfr[j], acc[i][j], 0, 0, 0);
                if (MODE)
                    acc[i][j] = __builtin_amdgcn_mfma_f32_16x16x32_bf16(al[i], bfr[j], acc[i][j], 0, 0, 0);
            }

        // ---- step edge: drain ds_reads; counted-wait next buf; barrier ----
        asm volatile("s_waitcnt lgkmcnt(0)" ::: "memory");
        __builtin_amdgcn_sched_barrier(0);
        if (s + 2 < nsteps)      { asm volatile("s_waitcnt vmcnt(6)" ::: "memory"); }
        else if (s + 1 < nsteps) { asm volatile("s_waitcnt vmcnt(0)" ::: "memory"); }
        __builtin_amdgcn_s_barrier();
        __builtin_amdgcn_sched_barrier(0);

        cur = (cur == 2) ? 0 : cur + 1;
        stg = (stg == 2) ? 0 : stg + 1;
    }

    // ---- epilogue: C/D layout col=lane&15, row=quad*4+reg; wave owns cols wave*64.. ----
    if (MODE == 0) {
        #pragma unroll
        for (int i = 0; i < 4; ++i)
            #pragma unroll
            for (int r = 0; r < 4; ++r) {
                int m = bm + i * 16 + quad * 4 + r;
                if (m < M) {
                    #pragma unroll
                    for (int j = 0; j < 4; ++j)
                        C[(size_t)m * HD + wave * 64 + j * 16 + l15] = acc[i][j][r];
                }
            }
    } else {
        int head = wave;                      // wave's 64 cols == one head
        float as[4], ad2[4];
        #pragma unroll
        for (int j = 0; j < 4; ++j) {
            as[j]  = a_src[head * DIM + j * 16 + l15];
            ad2[j] = a_dst[head * DIM + j * 16 + l15];
        }
        #pragma unroll
        for (int i = 0; i < 4; ++i)
            #pragma unroll
            for (int r = 0; r < 4; ++r) {
                int m = bm + i * 16 + quad * 4 + r;
                bool ok = m < M;
                float s = 0.f, t = 0.f;
                #pragma unroll
                for (int j = 0; j < 4; ++j) {
                    float v = acc[i][j][r];
                    if (ok) Hbf[(size_t)m * HD + head * DIM + j * 16 + l15] = (__bf16)v;
                    s += v * as[j];
                    t += v * ad2[j];
                }
                #pragma unroll
                for (int mask = 1; mask <= 8; mask <<= 1) {
                    s += __shfl_xor(s, mask, 64);
                    t += __shfl_xor(t, mask, 64);
                }
                if (ok && l15 == 0) {
                    atts[m * HEADS + head] = s;
                    attd[m * HEADS + head] = t;
                }
            }
    }
}

// ---------------- GAT edge-softmax + aggregation: wave-per-node, 4 heads fused ----------------
__global__ __launch_bounds__(256) void gat_agg(const __bf16* __restrict__ hW,
                                               const float* __restrict__ att_s,
                                               const float* __restrict__ att_d,
                                               const int* __restrict__ row_ptr,
                                               const int* __restrict__ csr_src,
                                               float* __restrict__ out, int N) {
    int n = blockIdx.x * 4 + (threadIdx.x >> 6);
    if (n >= N) return;
    int lane = threadIdx.x & 63;
    int sub  = lane >> 4;     // edge slot within 4-edge group
    int dq   = lane & 15;     // dim quarter within a head
    int r0 = row_ptr[n], deg = row_ptr[n + 1] - r0;
    f32x4 ad4 = *(const f32x4*)&att_d[n * HEADS];

    f32x4 acc[4];             // [head][4 dims]
    #pragma unroll
    for (int h = 0; h < HEADS; ++h) acc[h] = (f32x4){0.f, 0.f, 0.f, 0.f};
    f32x4 wsum4 = (f32x4){0.f, 0.f, 0.f, 0.f};

    if (deg <= 64) {
        bool act = lane < deg;
        int sj = act ? csr_src[r0 + lane] : 0;
        f32x4 a4 = act ? *(const f32x4*)&att_s[sj * HEADS] : (f32x4){0.f, 0.f, 0.f, 0.f};
        f32x4 x4;
        #pragma unroll
        for (int h = 0; h < HEADS; ++h) {
            float v = a4[h] + ad4[h];
            v = (v >= 0.f) ? v : 0.2f * v;
            x4[h] = act ? v : -INFINITY;
        }
        f32x4 m4 = x4;
        for (int off = 32; off > 0; off >>= 1)
            #pragma unroll
            for (int h = 0; h < HEADS; ++h)
                m4[h] = fmaxf(m4[h], __shfl_xor(m4[h], off, 64));
        f32x4 w4;
        #pragma unroll
        for (int h = 0; h < HEADS; ++h)
            w4[h] = act ? expf(x4[h] - m4[h]) : 0.f;
        wsum4 = w4;

        for (int g0 = 0; g0 < deg; g0 += 4) {
            int e  = g0 + sub;
            int ec = min(e, deg - 1);
            int se = __shfl(sj, ec, 64);
            bool eact = e < deg;
            #pragma unroll
            for (int h = 0; h < HEADS; ++h) {
                float wh = __shfl(w4[h], ec, 64);
                if (!eact) wh = 0.f;
                bf16x4 v = *(const bf16x4*)&hW[(size_t)se * HD + h * DIM + dq * 4];
                #pragma unroll
                for (int c = 0; c < 4; ++c) acc[h][c] += wh * (float)v[c];
            }
        }
    } else {
        f32x4 m4 = (f32x4){-INFINITY, -INFINITY, -INFINITY, -INFINITY};
        for (int base = 0; base < deg; base += 64) {
            int i = base + lane;
            bool act = i < deg;
            int sj = act ? csr_src[r0 + i] : 0;
            f32x4 a4 = act ? *(const f32x4*)&att_s[sj * HEADS] : (f32x4){0.f, 0.f, 0.f, 0.f};
            #pragma unroll
            for (int h = 0; h < HEADS; ++h) {
                float v = a4[h] + ad4[h];
                v = (v >= 0.f) ? v : 0.2f * v;
                m4[h] = fmaxf(m4[h], act ? v : -INFINITY);
            }
        }
        for (int off = 32; off > 0; off >>= 1)
            #pragma unroll
            for (int h = 0; h < HEADS; ++h)
                m4[h] = fmaxf(m4[h], __shfl_xor(m4[h], off, 64));

        for (int base = 0; base < deg; base += 64) {
            int i = base + lane;
            bool act = i < deg;
            int sj = act ? csr_src[r0 + i] : 0;
            f32x4 a4 = act ? *(const f32x4*)&att_s[sj * HEADS] : (f32x4){0.f, 0.f, 0.f, 0.f};
            f32x4 w4;
            #pragma unroll
            for (int h = 0; h < HEADS; ++h) {
                float v = a4[h] + ad4[h];
                v = (v >= 0.f) ? v : 0.2f * v;
                w4[h] = act ? expf(v - m4[h]) : 0.f;
            }
            #pragma unroll
            for (int h = 0; h < HEADS; ++h) wsum4[h] += w4[h];
            int cnt = min(64, deg - base);
            for (int g0 = 0; g0 < cnt; g0 += 4) {
                int e  = g0 + sub;
                int ec = min(e, cnt - 1);
                int se = __shfl(sj, ec, 64);
                bool eact = e < cnt;
                #pragma unroll
                for (int h = 0; h < HEADS; ++h) {
                    float wh = __shfl(w4[h], ec, 64);
                    if (!eact) wh = 0.f;
                    bf16x4 v = *(const bf16x4*)&hW[(size_t)se * HD + h * DIM + dq * 4];
                    #pragma unroll
                    for (int c = 0; c < 4; ++c) acc[h][c] += wh * (float)v[c];
                }
            }
        }
    }

    #pragma unroll
    for (int h = 0; h < HEADS; ++h)
        #pragma unroll
        for (int c = 0; c < 4; ++c) {
            acc[h][c] += __shfl_xor(acc[h][c], 16, 64);
            acc[h][c] += __shfl_xor(acc[h][c], 32, 64);
        }
    for (int off = 32; off > 0; off >>= 1)
        #pragma unroll
        for (int h = 0; h < HEADS; ++h)
            wsum4[h] += __shfl_xor(wsum4[h], off, 64);

    if (sub == 0) {
        #pragma unroll
        for (int h = 0; h < HEADS; ++h) {
            float inv = 1.f / (wsum4[h] + 1e-9f);
            f32x4 o;
            #pragma unroll
            for (int c = 0; c < 4; ++c) {
                float v = acc[h][c] * inv;
                o[c] = (v > 0.f) ? v : expm1f(v);  // ELU
            }
            *(f32x4*)&out[(size_t)n * HD + h * DIM + dq * 4] = o;
        }
    }
}

// ---------------- mean pool per graph + final linear (f32 output) ----------------
__global__ __launch_bounds__(256) void pool_out(const float* __restrict__ h,
                                                const int* __restrict__ gid,
                                                const float* __restrict__ W_out,
                                                const float* __restrict__ b_out,
                                                const float* __restrict__ scores,
                                                float* __restrict__ out, int N) {
    int b = blockIdx.x;
    int j = threadIdx.x;
    int l = 0, r = N;
    while (l < r) { int mid = (l + r) >> 1; if (gid[mid] < b) l = mid + 1; else r = mid; }
    int lo = l;
    r = N;
    while (l < r) { int mid = (l + r) >> 1; if (gid[mid] < b + 1) l = mid + 1; else r = mid; }
    int hi = l;

    float sum = 0.f;
    for (int n = lo; n < hi; ++n) sum += h[(size_t)n * HD + j];
    int cnt = hi - lo;
    float pooled = sum / fmaxf((float)cnt, 1.f);
    float val = pooled * W_out[j];

    __shared__ float red[256];
    red[j] = val;
    __syncthreads();
    for (int s = 128; s > 0; s >>= 1) {
        if (j < s) red[j] += red[j + s];
        __syncthreads();
    }
    if (j == 0) {
        out[b] = red[0] + scores[b] * W_out[HD] + b_out[0];
    }
}

// ---------------- host ----------------

static inline size_t al256(size_t x) { return (x + 255) & ~(size_t)255; }

#define KP_LIG  96
#define KP_PROT 1280
#define KP_HID  256

extern "C" void kernel_launch(void* const* d_in, const int* in_sizes, int n_in,
                              void* d_out, int out_size, void* d_ws, size_t ws_size,
                              hipStream_t stream) {
    const float* ligand_x  = (const float*)d_in[0];
    const float* protein_x = (const float*)d_in[1];
    const float* W_lig     = (const float*)d_in[2];
    const float* W_prot    = (const float*)d_in[3];
    const float* W1        = (const float*)d_in[4];
    const float* a1_src    = (const float*)d_in[5];
    const float* a1_dst    = (const float*)d_in[6];
    const float* W2        = (const float*)d_in[7];
    const float* a2_src    = (const float*)d_in[8];
    const float* a2_dst    = (const float*)d_in[9];
    const float* W_out     = (const float*)d_in[10];
    const float* b_out     = (const float*)d_in[11];
    const int*   edge_src  = (const int*)d_in[12];
    const int*   edge_dst  = (const int*)d_in[13];
    const int*   graph_ids = (const int*)d_in[14];
    const float* scores    = (const float*)d_in[15];
    float* out = (float*)d_out;

    // workspace layout
    char* w = (char*)d_ws;
    float*  xbuf = (float*)w;           w += al256((size_t)NN * HD * 4);
    __bf16* Hbf  = (__bf16*)w;          w += al256((size_t)NN * HD * 2);
    float* atts = (float*)w;            w += al256((size_t)NN * HEADS * 4);
    float* attd = (float*)w;            w += al256((size_t)NN * HEADS * 4);
    int* counts  = (int*)w;             w += al256((size_t)NN * 4);
    int* incl    = (int*)w;             w += al256((size_t)NN * 4);
    int* bsum    = (int*)w;             w += al256(64 * 4);
    int* row_ptr = (int*)w;             w += al256((size_t)(NN + 1) * 4);
    int* cursor  = (int*)w;             w += al256((size_t)NN * 4);
    int* csr_src = (int*)w;             w += al256((size_t)EDGES * 4);
    __bf16* Bt_lig  = (__bf16*)w;       w += al256((size_t)HD * KP_LIG * 2);
    __bf16* Bt_prot = (__bf16*)w;       w += al256((size_t)HD * KP_PROT * 2);
    __bf16* Bt_W1   = (__bf16*)w;       w += al256((size_t)HD * KP_HID * 2);
    __bf16* Bt_W2   = (__bf16*)w;       w += al256((size_t)HD * KP_HID * 2);
    float* Apad     = (float*)w;        w += al256((size_t)N_LIG * KP_LIG * 4);

    const int NB_SCAN = (NN + 1023) / 1024;  // 49

    hipMemsetAsync(counts, 0, (size_t)NN * 4, stream);
    hipMemsetAsync(cursor, 0, (size_t)NN * 4, stream);

    // --- weight convert/transpose to bf16; ligand A zero-pad to K=96 ---
    k_wcvt<<<HD, 256, 0, stream>>>(W_lig,  Bt_lig,  F_LIG,  KP_LIG);
    k_wcvt<<<HD, 256, 0, stream>>>(W_prot, Bt_prot, F_PROT, KP_PROT);
    k_wcvt<<<HD, 256, 0, stream>>>(W1,     Bt_W1,   HD,     KP_HID);
    k_wcvt<<<HD, 256, 0, stream>>>(W2,     Bt_W2,   HD,     KP_HID);
    k_apad<<<N_LIG, 128, 0, stream>>>(ligand_x, Apad);

    // --- CSR by destination ---
    k_hist<<<(EDGES + 255) / 256, 256, 0, stream>>>(edge_dst, counts, EDGES);
    k_scan1<<<NB_SCAN, 1024, 0, stream>>>(counts, incl, bsum, NN);
    k_scan2<<<1, 1, 0, stream>>>(bsum, NB_SCAN, row_ptr, NN, EDGES);
    k_scan3<<<NB_SCAN, 1024, 0, stream>>>(incl, counts, bsum, row_ptr, NN);
    k_scatter<<<(EDGES + 255) / 256, 256, 0, stream>>>(edge_src, edge_dst, row_ptr,
                                                       cursor, csr_src, EDGES);

    // --- input projections -> xbuf [NN,256] (64x256-tile counted GEMM) ---
    {
        int nwg = (N_LIG + 63) / 64;
        mfma_gemm<0><<<nwg, 256, 0, stream>>>(
            Apad, Bt_lig, xbuf, nullptr, nullptr, nullptr, nullptr, nullptr,
            N_LIG, KP_LIG, KP_LIG, nwg);
    }
    {
        int nwg = (N_PROT + 63) / 64;
        mfma_gemm<0><<<nwg, 256, 0, stream>>>(
            protein_x, Bt_prot, xbuf + (size_t)N_LIG * HD, nullptr, nullptr, nullptr,
            nullptr, nullptr, N_PROT, KP_PROT, KP_PROT, nwg);
    }

    // --- GAT layer 1: GEMM (+fused att, bf16 h) -> gather ---
    {
        int nwg = (NN + 63) / 64;
        mfma_gemm<1><<<nwg, 256, 0, stream>>>(
            xbuf, Bt_W1, nullptr, Hbf, atts, attd, a1_src, a1_dst, NN, KP_HID, KP_HID, nwg);
    }
    gat_agg<<<(NN + 3) / 4, 256, 0, stream>>>(Hbf, atts, attd, row_ptr, csr_src, xbuf, NN);

    // --- GAT layer 2 ---
    {
        int nwg = (NN + 63) / 64;
        mfma_gemm<1><<<nwg, 256, 0, stream>>>(
            xbuf, Bt_W2, nullptr, Hbf, atts, attd, a2_src, a2_dst, NN, KP_HID, KP_HID, nwg);
    }
    gat_agg<<<(NN + 3) / 4, 256, 0, stream>>>(Hbf, atts, attd, row_ptr, csr_src, xbuf, NN);

    // --- pool + final linear ---
    pool_out<<<BATCH, 256, 0, stream>>>(xbuf, graph_ids, W_out, b_out, scores, out, NN);
}